// Round 5
// baseline (1566.829 us; speedup 1.0000x reference)
//
#include <hip/hip_runtime.h>
#include <math.h>

constexpr int N_NODES = 4096;
constexpr int N_EDGES = 65536;
constexpr int D_INF   = 64;
constexpr int H       = 128;
constexpr int T       = 8;
constexpr int B       = 8;
constexpr int M       = B * N_NODES;   // 32768 rows per GEMM

typedef __attribute__((ext_vector_type(8))) short bf16x8;
typedef __attribute__((ext_vector_type(4))) float f32x4;

__device__ inline unsigned short f2bf(float x) {
  unsigned int u = __float_as_uint(x);
  unsigned int r = (u + 0x7fffu + ((u >> 16) & 1u)) >> 16;
  return (unsigned short)r;
}
__device__ inline float bf2f(unsigned short b) {
  return __uint_as_float((unsigned int)b << 16);
}

// ---------------- CSR build ----------------

__global__ void k_count(const int* __restrict__ dst, int* __restrict__ cnt) {
  int e = blockIdx.x * blockDim.x + threadIdx.x;
  if (e < N_EDGES) atomicAdd(&cnt[dst[e]], 1);
}

__global__ void k_dinv(const int* __restrict__ cnt, float* __restrict__ dinv) {
  int n = blockIdx.x * blockDim.x + threadIdx.x;
  if (n < N_NODES) dinv[n] = 1.0f / sqrtf((float)cnt[n] + 2.0f);
}

__global__ void k_scan(const int* __restrict__ cnt, int* __restrict__ rowptr) {
  __shared__ int sums[1024];
  int t = threadIdx.x;
  int v0 = cnt[4*t+0], v1 = cnt[4*t+1], v2 = cnt[4*t+2], v3 = cnt[4*t+3];
  int s0 = v0, s1 = s0 + v1, s2 = s1 + v2, s3 = s2 + v3;
  sums[t] = s3;
  __syncthreads();
  for (int off = 1; off < 1024; off <<= 1) {
    int x = (t >= off) ? sums[t - off] : 0;
    __syncthreads();
    sums[t] += x;
    __syncthreads();
  }
  int base = (t > 0) ? sums[t - 1] : 0;
  if (t == 0) rowptr[0] = 0;
  rowptr[4*t+1] = base + s0;
  rowptr[4*t+2] = base + s1;
  rowptr[4*t+3] = base + s2;
  rowptr[4*t+4] = base + s3;
}

__global__ void k_fill(const int* __restrict__ src, const int* __restrict__ dst,
                       const float* __restrict__ dinv, const int* __restrict__ rowptr,
                       int* __restrict__ fill, int2* __restrict__ eg) {
  int e = blockIdx.x * blockDim.x + threadIdx.x;
  if (e >= N_EDGES) return;
  int s = src[e], d = dst[e];
  int p = rowptr[d] + atomicAdd(&fill[d], 1);
  eg[p] = make_int2(s, __float_as_int(dinv[s] * dinv[d]));
}

// ---------------- W pack: gate-interleaved cols + MFMA fragment order + hi/lo ----
__global__ void k_pack(const float* __restrict__ W, unsigned short* __restrict__ Bp,
                       int K) {
  int tid = blockIdx.x * 256 + threadIdx.x;
  if (tid >= K * 64) return;
  int lane = tid & 63;
  int ntg  = (tid >> 6) & 31;
  int kb   = tid >> 11;
  int gate = ntg & 3, fg = ntg >> 2;
  int corig = gate * 128 + fg * 16 + (lane & 15);
  int k0 = kb * 32 + (lane >> 4) * 8;
  long obase = ((long)(kb * 32 + ntg) * 64 + lane) * 8;
  long plane = (long)K * 512;
  #pragma unroll
  for (int j = 0; j < 8; ++j) {
    float v = W[(long)(k0 + j) * 512 + corig];
    unsigned short h = f2bf(v);
    Bp[obase + j]         = h;
    Bp[plane + obase + j] = f2bf(v - bf2f(h));
  }
}

// ---------------- phase-striped SpMM, NT streams ----------------
// Gathers ONE source plane X (row width F), writes stripe [C0,C0+F) of Ah/Al
// (row width Ktot). Wave = one (b,n) node; G = 256/F edges per iteration.
// eg loads + Ah/Al stores are NONTEMPORAL so the 2 MB gather slab stays in L2.
template<int F>
__device__ __forceinline__ void spmm_body(
    const int* __restrict__ rowptr, const int2* __restrict__ eg,
    const float* __restrict__ dinv,
    const float* __restrict__ X, long bstride, int C0, int Ktot,
    unsigned short* __restrict__ Ah, unsigned short* __restrict__ Al) {
  constexpr int LPG = F / 4;        // lanes per edge (16 or 32)
  constexpr int G   = 64 / LPG;     // edges per iteration (4 or 2)
  int tid  = threadIdx.x;
  int wid  = tid >> 6;
  int lane = tid & 63;
  int j    = blockIdx.x;                        // 8192 blocks
  int obk  = (j & 7) * 1024 + (j >> 3);         // XCD j%8 <-> batch
  int node = obk * 4 + wid;
  int b = node >> 12, n = node & (N_NODES - 1);
  int g  = lane / LPG;
  int l  = lane % LPG;
  int c4 = l * 4;
  const float* Xb = X + (long)b * bstride;
  f32x4 acc = {0.f, 0.f, 0.f, 0.f};
  int rs = rowptr[n], re = rowptr[n + 1];
  int e = rs + g;
  for (; e + G < re; e += 2 * G) {
    long long r0 = __builtin_nontemporal_load((const long long*)&eg[e]);
    long long r1 = __builtin_nontemporal_load((const long long*)&eg[e + G]);
    int   c0 = (int)r0,  c1 = (int)r1;
    float w0 = __int_as_float((int)(r0 >> 32));
    float w1 = __int_as_float((int)(r1 >> 32));
    f32x4 v0 = *(const f32x4*)(Xb + (long)c0 * F + c4);
    f32x4 v1 = *(const f32x4*)(Xb + (long)c1 * F + c4);
    acc += w0 * v0;
    acc += w1 * v1;
  }
  if (e < re) {
    long long r0 = __builtin_nontemporal_load((const long long*)&eg[e]);
    f32x4 v0 = *(const f32x4*)(Xb + (long)(int)r0 * F + c4);
    acc += __int_as_float((int)(r0 >> 32)) * v0;
  }
  #pragma unroll
  for (int off = LPG; off < 64; off <<= 1) {
    acc[0] += __shfl_xor(acc[0], off, 64);
    acc[1] += __shfl_xor(acc[1], off, 64);
    acc[2] += __shfl_xor(acc[2], off, 64);
    acc[3] += __shfl_xor(acc[3], off, 64);
  }
  if (g == 0) {
    float dn = dinv[n];
    float sw = 2.0f * dn * dn;
    f32x4 v = *(const f32x4*)(Xb + (long)n * F + c4);
    acc += sw * v;
    unsigned short hs[4], ls[4];
    #pragma unroll
    for (int jj = 0; jj < 4; ++jj) {
      unsigned short h = f2bf(acc[jj]);
      hs[jj] = h;
      ls[jj] = f2bf(acc[jj] - bf2f(h));
    }
    unsigned long long hv =
        (unsigned long long)((unsigned)hs[0] | ((unsigned)hs[1] << 16)) |
        ((unsigned long long)((unsigned)hs[2] | ((unsigned)hs[3] << 16)) << 32);
    unsigned long long lv =
        (unsigned long long)((unsigned)ls[0] | ((unsigned)ls[1] << 16)) |
        ((unsigned long long)((unsigned)ls[2] | ((unsigned)ls[3] << 16)) << 32);
    __builtin_nontemporal_store(hv,
        (unsigned long long*)(Ah + (long)node * Ktot + C0 + c4));
    __builtin_nontemporal_store(lv,
        (unsigned long long*)(Al + (long)node * Ktot + C0 + c4));
  }
}

// blockIdx.y selects the source plane (0: X1 stripe [0,F1), 1: X2 stripe [F1,F1+F2))
template<int F1, int F2>
__global__ __launch_bounds__(256) void k_spmm3(
    const int* __restrict__ rowptr, const int2* __restrict__ eg,
    const float* __restrict__ dinv,
    const float* __restrict__ X1, long bs1,
    const float* __restrict__ X2, long bs2, int Ktot,
    unsigned short* __restrict__ Ah, unsigned short* __restrict__ Al) {
  if (blockIdx.y == 0)
    spmm_body<F1>(rowptr, eg, dinv, X1, bs1, 0, Ktot, Ah, Al);
  else
    spmm_body<F2>(rowptr, eg, dinv, X2, bs2, F1, Ktot, Ah, Al);
}

// ---------------- MFMA GEMM (split-bf16, 3-term) + fused LSTM ----------------
// block = 4 waves = one 64-row tile x all 512 cols. Each wave: 2 fg groups,
// processed sequentially (ff loop) to cap VGPRs. A staged once (NT loads),
// fragment-linear LDS -> conflict-free ds_read_b128.
template<int K>
__global__ __launch_bounds__(256, 2) void k_gemm_lstm(
    const unsigned short* __restrict__ Ah, const unsigned short* __restrict__ Al,
    const unsigned short* __restrict__ Bp, const float* __restrict__ bias,
    float* __restrict__ hbuf, float* __restrict__ cbuf,
    float* __restrict__ out2, int t) {
  constexpr int KB = K / 32;
  __shared__ __align__(16) unsigned short At[8 * KB * 64 * 8];  // 48/64 KB
  int tid  = threadIdx.x;
  int j    = blockIdx.x;                          // 512 blocks
  int mblk = (j & 7) * 64 + (j >> 3);             // XCD-align with producer batch
  int m0   = mblk * 64;
  int lane = tid & 63;
  int w    = tid >> 6;

  // stage: chunk = ((pm*KB + kb)*64 + lane), pm = plane*4 + mt
  constexpr int NCH = 8 * KB * 64;
  #pragma unroll
  for (int it = 0; it < NCH / 256; ++it) {
    int chunk = it * 256 + tid;
    int cl = chunk & 63;
    int t1 = chunk >> 6;
    int kb = t1 % KB;
    int pm = t1 / KB;
    int mt = pm & 3, pl = pm >> 2;
    const unsigned short* sp = (pl ? Al : Ah)
        + (long)(m0 + mt * 16 + (cl & 15)) * K + kb * 32 + (cl >> 4) * 8;
    long long q0 = __builtin_nontemporal_load((const long long*)sp);
    long long q1 = __builtin_nontemporal_load((const long long*)sp + 1);
    *(long long*)(At + (long)chunk * 8)     = q0;
    *(long long*)(At + (long)chunk * 8 + 4) = q1;
  }
  __syncthreads();

  int fgb = w * 2;
  int l15 = lane & 15, lq = lane >> 4;

  #pragma unroll
  for (int ff = 0; ff < 2; ++ff) {
    const unsigned short* bb  = Bp + (long)((fgb + ff) * 4) * 512 + lane * 8;
    const unsigned short* blp = bb + (long)K * 512;

    f32x4 acc[4][4];
    #pragma unroll
    for (int mt = 0; mt < 4; ++mt)
      #pragma unroll
      for (int gt = 0; gt < 4; ++gt)
        acc[mt][gt] = (f32x4){0.f, 0.f, 0.f, 0.f};

    for (int kb = 0; kb < KB; ++kb) {
      bf16x8 AH_[4], AL_[4];
      #pragma unroll
      for (int mt = 0; mt < 4; ++mt) {
        AH_[mt] = *(const bf16x8*)(At + (((mt)     * KB + kb) * 64 + lane) * 8);
        AL_[mt] = *(const bf16x8*)(At + (((4 + mt) * KB + kb) * 64 + lane) * 8);
      }
      bf16x8 BH[4], BL[4];
      #pragma unroll
      for (int gt = 0; gt < 4; ++gt) {
        BH[gt] = *(const bf16x8*)(bb  + ((long)kb * 32 + gt) * 512);
        BL[gt] = *(const bf16x8*)(blp + ((long)kb * 32 + gt) * 512);
      }
      #pragma unroll
      for (int gt = 0; gt < 4; ++gt) {
        #pragma unroll
        for (int mt = 0; mt < 4; ++mt) {
          acc[mt][gt] = __builtin_amdgcn_mfma_f32_16x16x32_bf16(AH_[mt], BH[gt], acc[mt][gt], 0, 0, 0);
          acc[mt][gt] = __builtin_amdgcn_mfma_f32_16x16x32_bf16(AL_[mt], BH[gt], acc[mt][gt], 0, 0, 0);
          acc[mt][gt] = __builtin_amdgcn_mfma_f32_16x16x32_bf16(AH_[mt], BL[gt], acc[mt][gt], 0, 0, 0);
        }
      }
    }

    int f = (fgb + ff) * 16 + l15;
    float bi = bias[f], bff = bias[128 + f], bo = bias[256 + f], bg = bias[384 + f];
    #pragma unroll
    for (int mt = 0; mt < 4; ++mt) {
      #pragma unroll
      for (int r = 0; r < 4; ++r) {
        int m = m0 + mt * 16 + lq * 4 + r;
        float vi = 1.0f / (1.0f + __expf(-(acc[mt][0][r] + bi)));
        float vf = 1.0f / (1.0f + __expf(-(acc[mt][1][r] + bff)));
        float vo = 1.0f / (1.0f + __expf(-(acc[mt][2][r] + bo)));
        float vg = tanhf(acc[mt][3][r] + bg);
        long idx = (long)m * H + f;
        float cn = vf * cbuf[idx] + vi * vg;
        float hn = vo * tanhf(cn);
        cbuf[idx] = cn;
        hbuf[idx] = hn;
        if (out2) {
          int bb2 = m >> 12, nn = m & (N_NODES - 1);
          __builtin_nontemporal_store(hn,
              &out2[(((long)bb2 * T + t) * N_NODES + nn) * H + f]);
        }
      }
    }
  }
}

// ---------------- launch ----------------

extern "C" void kernel_launch(void* const* d_in, const int* in_sizes, int n_in,
                              void* d_out, int out_size, void* d_ws, size_t ws_size,
                              hipStream_t stream) {
  const float* x  = (const float*)d_in[0];
  const float* W0 = (const float*)d_in[1];
  const float* b0 = (const float*)d_in[2];
  const float* W1 = (const float*)d_in[3];
  const float* b1 = (const float*)d_in[4];
  const int*   ei = (const int*)d_in[5];
  const int* srcp = ei;
  const int* dstp = ei + N_EDGES;
  float* out = (float*)d_out;

  char* p = (char*)d_ws;
  auto alloc = [&](size_t bytes) {
    char* r = p;
    p += (bytes + 255) & ~(size_t)255;
    return r;
  };
  int*   cnt    = (int*)  alloc(N_NODES * 4);
  int*   fill   = (int*)  alloc(N_NODES * 4);
  float* dinv   = (float*)alloc(N_NODES * 4);
  int*   rowptr = (int*)  alloc((N_NODES + 1) * 4);
  int2*  eg     = (int2*) alloc((size_t)N_EDGES * 8);
  float* hc     = (float*)alloc((size_t)4 * M * H * 4);     // h0,c0,h1,c1 fp32
  unsigned short* Ah  = (unsigned short*)alloc((size_t)M * 256 * 2);
  unsigned short* Al  = (unsigned short*)alloc((size_t)M * 256 * 2);
  unsigned short* Bp0 = (unsigned short*)alloc((size_t)192 * 512 * 2 * 2);
  unsigned short* Bp1 = (unsigned short*)alloc((size_t)256 * 512 * 2 * 2);
  float* h0 = hc;
  float* c0 = hc + (size_t)M * H;
  float* h1 = hc + (size_t)2 * M * H;
  float* c1 = hc + (size_t)3 * M * H;

  hipMemsetAsync(cnt,  0, N_NODES * 4, stream);
  hipMemsetAsync(fill, 0, N_NODES * 4, stream);
  hipMemsetAsync(hc,   0, (size_t)4 * M * H * 4, stream);

  k_count<<<N_EDGES / 256, 256, 0, stream>>>(dstp, cnt);
  k_dinv <<<N_NODES / 256, 256, 0, stream>>>(cnt, dinv);
  k_scan <<<1, 1024, 0, stream>>>(cnt, rowptr);
  k_fill <<<N_EDGES / 256, 256, 0, stream>>>(srcp, dstp, dinv, rowptr, fill, eg);
  k_pack <<<(192 * 64 + 255) / 256, 256, 0, stream>>>(W0, Bp0, 192);
  k_pack <<<(256 * 64 + 255) / 256, 256, 0, stream>>>(W1, Bp1, 256);

  for (int t = 0; t < T; ++t) {
    // layer 0: A = A_hat @ [x_t | h0]   (K = 192), two striped passes, one launch
    k_spmm3<D_INF, H><<<dim3(M / 4, 2), 256, 0, stream>>>(rowptr, eg, dinv,
        x + (size_t)t * N_NODES * D_INF, (long)T * N_NODES * D_INF,
        h0, (long)N_NODES * H, 192, Ah, Al);
    k_gemm_lstm<192><<<512, 256, 0, stream>>>(Ah, Al, Bp0, b0, h0, c0, nullptr, t);
    // layer 1: A = A_hat @ [h0_t | h1]  (K = 256)
    k_spmm3<H, H><<<dim3(M / 4, 2), 256, 0, stream>>>(rowptr, eg, dinv,
        h0, (long)N_NODES * H, h1, (long)N_NODES * H, 256, Ah, Al);
    k_gemm_lstm<256><<<512, 256, 0, stream>>>(Ah, Al, Bp1, b1, h1, c1, out, t);
  }
}

// Round 7
// 1391.731 us; speedup vs baseline: 1.1258x; 1.1258x over previous
//
#include <hip/hip_runtime.h>
#include <hip/hip_fp16.h>
#include <math.h>

constexpr int N_NODES = 4096;
constexpr int N_EDGES = 65536;
constexpr int D_INF   = 64;
constexpr int H       = 128;
constexpr int T       = 8;
constexpr int B       = 8;
constexpr int M       = B * N_NODES;   // 32768 rows per GEMM

typedef __attribute__((ext_vector_type(8))) short bf16x8;
typedef __attribute__((ext_vector_type(4))) float f32x4;
typedef __attribute__((ext_vector_type(8))) _Float16 f16x8;
typedef __attribute__((ext_vector_type(4))) unsigned int u32x4;

__device__ inline unsigned short f2bf(float x) {
  unsigned int u = __float_as_uint(x);
  unsigned int r = (u + 0x7fffu + ((u >> 16) & 1u)) >> 16;
  return (unsigned short)r;
}
__device__ inline float bf2f(unsigned short b) {
  return __uint_as_float((unsigned int)b << 16);
}

// ---------------- CSR build ----------------

__global__ void k_count(const int* __restrict__ dst, int* __restrict__ cnt) {
  int e = blockIdx.x * blockDim.x + threadIdx.x;
  if (e < N_EDGES) atomicAdd(&cnt[dst[e]], 1);
}

__global__ void k_dinv(const int* __restrict__ cnt, float* __restrict__ dinv) {
  int n = blockIdx.x * blockDim.x + threadIdx.x;
  if (n < N_NODES) dinv[n] = 1.0f / sqrtf((float)cnt[n] + 2.0f);
}

__global__ void k_scan(const int* __restrict__ cnt, int* __restrict__ rowptr) {
  __shared__ int sums[1024];
  int t = threadIdx.x;
  int v0 = cnt[4*t+0], v1 = cnt[4*t+1], v2 = cnt[4*t+2], v3 = cnt[4*t+3];
  int s0 = v0, s1 = s0 + v1, s2 = s1 + v2, s3 = s2 + v3;
  sums[t] = s3;
  __syncthreads();
  for (int off = 1; off < 1024; off <<= 1) {
    int x = (t >= off) ? sums[t - off] : 0;
    __syncthreads();
    sums[t] += x;
    __syncthreads();
  }
  int base = (t > 0) ? sums[t - 1] : 0;
  if (t == 0) rowptr[0] = 0;
  rowptr[4*t+1] = base + s0;
  rowptr[4*t+2] = base + s1;
  rowptr[4*t+3] = base + s2;
  rowptr[4*t+4] = base + s3;
}

__global__ void k_fill(const int* __restrict__ src, const int* __restrict__ dst,
                       const float* __restrict__ dinv, const int* __restrict__ rowptr,
                       int* __restrict__ fill, int2* __restrict__ eg) {
  int e = blockIdx.x * blockDim.x + threadIdx.x;
  if (e >= N_EDGES) return;
  int s = src[e], d = dst[e];
  int p = rowptr[d] + atomicAdd(&fill[d], 1);
  eg[p] = make_int2(s, __float_as_int(dinv[s] * dinv[d]));
}

// ---------------- W pack: gate-interleaved cols + MFMA fragment order + hi/lo ----
__global__ void k_pack(const float* __restrict__ W, unsigned short* __restrict__ Bp,
                       int K) {
  int tid = blockIdx.x * 256 + threadIdx.x;
  if (tid >= K * 64) return;
  int lane = tid & 63;
  int ntg  = (tid >> 6) & 31;
  int kb   = tid >> 11;
  int gate = ntg & 3, fg = ntg >> 2;
  int corig = gate * 128 + fg * 16 + (lane & 15);
  int k0 = kb * 32 + (lane >> 4) * 8;
  long obase = ((long)(kb * 32 + ntg) * 64 + lane) * 8;
  long plane = (long)K * 512;
  #pragma unroll
  for (int j = 0; j < 8; ++j) {
    float v = W[(long)(k0 + j) * 512 + corig];
    unsigned short h = f2bf(v);
    Bp[obase + j]         = h;
    Bp[plane + obase + j] = f2bf(v - bf2f(h));
  }
}

// ---------------- striped SpMM bodies ----------------
// fp32 source (x): lane covers 4 feats (16B); fp16 source (h): 8 feats (16B).
// Writes stripe [C0, C0+F) of Ah/Al (row width Ktot) as split-bf16.

template<int F>
__device__ __forceinline__ void spmm_body_f32(
    const int* __restrict__ rowptr, const int2* __restrict__ eg,
    const float* __restrict__ dinv,
    const float* __restrict__ X, long bstride, int C0, int Ktot,
    unsigned short* __restrict__ Ah, unsigned short* __restrict__ Al) {
  constexpr int LPG = F / 4;
  constexpr int G   = 64 / LPG;
  int tid  = threadIdx.x;
  int wid  = tid >> 6;
  int lane = tid & 63;
  int j    = blockIdx.x;
  int obk  = (j & 7) * 1024 + (j >> 3);         // XCD <-> batch
  int node = obk * 4 + wid;
  int b = node >> 12, n = node & (N_NODES - 1);
  int g  = lane / LPG;
  int l  = lane % LPG;
  int c4 = l * 4;
  const float* Xb = X + (long)b * bstride;
  float acc[4] = {0.f, 0.f, 0.f, 0.f};
  int rs = rowptr[n], re = rowptr[n + 1];
  int e = rs + g;
  for (; e + G < re; e += 2 * G) {
    long long r0 = __builtin_nontemporal_load((const long long*)&eg[e]);
    long long r1 = __builtin_nontemporal_load((const long long*)&eg[e + G]);
    float w0 = __int_as_float((int)(r0 >> 32));
    float w1 = __int_as_float((int)(r1 >> 32));
    f32x4 v0 = *(const f32x4*)(Xb + (long)(int)r0 * F + c4);
    f32x4 v1 = *(const f32x4*)(Xb + (long)(int)r1 * F + c4);
    #pragma unroll
    for (int q = 0; q < 4; ++q) acc[q] += w0 * v0[q] + w1 * v1[q];
  }
  if (e < re) {
    long long r0 = __builtin_nontemporal_load((const long long*)&eg[e]);
    f32x4 v0 = *(const f32x4*)(Xb + (long)(int)r0 * F + c4);
    float w0 = __int_as_float((int)(r0 >> 32));
    #pragma unroll
    for (int q = 0; q < 4; ++q) acc[q] += w0 * v0[q];
  }
  #pragma unroll
  for (int off = LPG; off < 64; off <<= 1)
    #pragma unroll
    for (int q = 0; q < 4; ++q) acc[q] += __shfl_xor(acc[q], off, 64);
  if (g == 0) {
    float dn = dinv[n];
    float sw = 2.0f * dn * dn;
    f32x4 v = *(const f32x4*)(Xb + (long)n * F + c4);
    #pragma unroll
    for (int q = 0; q < 4; ++q) acc[q] += sw * v[q];
    unsigned short hs[4], ls[4];
    #pragma unroll
    for (int q = 0; q < 4; ++q) {
      hs[q] = f2bf(acc[q]);
      ls[q] = f2bf(acc[q] - bf2f(hs[q]));
    }
    unsigned long long hv =
        (unsigned long long)((unsigned)hs[0] | ((unsigned)hs[1] << 16)) |
        ((unsigned long long)((unsigned)hs[2] | ((unsigned)hs[3] << 16)) << 32);
    unsigned long long lv =
        (unsigned long long)((unsigned)ls[0] | ((unsigned)ls[1] << 16)) |
        ((unsigned long long)((unsigned)ls[2] | ((unsigned)ls[3] << 16)) << 32);
    __builtin_nontemporal_store(hv,
        (unsigned long long*)(Ah + (long)node * Ktot + C0 + c4));
    __builtin_nontemporal_store(lv,
        (unsigned long long*)(Al + (long)node * Ktot + C0 + c4));
  }
}

template<int F>
__device__ __forceinline__ void spmm_body_f16(
    const int* __restrict__ rowptr, const int2* __restrict__ eg,
    const float* __restrict__ dinv,
    const _Float16* __restrict__ X, long bstride, int C0, int Ktot,
    unsigned short* __restrict__ Ah, unsigned short* __restrict__ Al) {
  constexpr int LPG = F / 8;        // 16 for F=128
  constexpr int G   = 64 / LPG;     // 4 edges/iter
  int tid  = threadIdx.x;
  int wid  = tid >> 6;
  int lane = tid & 63;
  int j    = blockIdx.x;
  int obk  = (j & 7) * 1024 + (j >> 3);
  int node = obk * 4 + wid;
  int b = node >> 12, n = node & (N_NODES - 1);
  int g  = lane / LPG;
  int l  = lane % LPG;
  int c8 = l * 8;
  const _Float16* Xb = X + (long)b * bstride;
  float acc[8] = {0.f,0.f,0.f,0.f,0.f,0.f,0.f,0.f};
  int rs = rowptr[n], re = rowptr[n + 1];
  int e = rs + g;
  for (; e + G < re; e += 2 * G) {
    long long r0 = __builtin_nontemporal_load((const long long*)&eg[e]);
    long long r1 = __builtin_nontemporal_load((const long long*)&eg[e + G]);
    float w0 = __int_as_float((int)(r0 >> 32));
    float w1 = __int_as_float((int)(r1 >> 32));
    f16x8 v0 = *(const f16x8*)(Xb + (long)(int)r0 * F + c8);
    f16x8 v1 = *(const f16x8*)(Xb + (long)(int)r1 * F + c8);
    #pragma unroll
    for (int q = 0; q < 8; ++q) acc[q] += w0 * (float)v0[q] + w1 * (float)v1[q];
  }
  if (e < re) {
    long long r0 = __builtin_nontemporal_load((const long long*)&eg[e]);
    f16x8 v0 = *(const f16x8*)(Xb + (long)(int)r0 * F + c8);
    float w0 = __int_as_float((int)(r0 >> 32));
    #pragma unroll
    for (int q = 0; q < 8; ++q) acc[q] += w0 * (float)v0[q];
  }
  #pragma unroll
  for (int off = LPG; off < 64; off <<= 1)
    #pragma unroll
    for (int q = 0; q < 8; ++q) acc[q] += __shfl_xor(acc[q], off, 64);
  if (g == 0) {
    float dn = dinv[n];
    float sw = 2.0f * dn * dn;
    f16x8 v = *(const f16x8*)(Xb + (long)n * F + c8);
    #pragma unroll
    for (int q = 0; q < 8; ++q) acc[q] += sw * (float)v[q];
    unsigned short hs[8], ls[8];
    #pragma unroll
    for (int q = 0; q < 8; ++q) {
      hs[q] = f2bf(acc[q]);
      ls[q] = f2bf(acc[q] - bf2f(hs[q]));
    }
    u32x4 hv, lv;
    hv.x = (unsigned)hs[0] | ((unsigned)hs[1] << 16);
    hv.y = (unsigned)hs[2] | ((unsigned)hs[3] << 16);
    hv.z = (unsigned)hs[4] | ((unsigned)hs[5] << 16);
    hv.w = (unsigned)hs[6] | ((unsigned)hs[7] << 16);
    lv.x = (unsigned)ls[0] | ((unsigned)ls[1] << 16);
    lv.y = (unsigned)ls[2] | ((unsigned)ls[3] << 16);
    lv.z = (unsigned)ls[4] | ((unsigned)ls[5] << 16);
    lv.w = (unsigned)ls[6] | ((unsigned)ls[7] << 16);
    __builtin_nontemporal_store(hv, (u32x4*)(Ah + (long)node * Ktot + C0 + c8));
    __builtin_nontemporal_store(lv, (u32x4*)(Al + (long)node * Ktot + C0 + c8));
  }
}

// layer 0: pass0 = x (fp32, F=64), pass1 = h0 (fp16, F=128)
__global__ __launch_bounds__(256) void k_spmm_l0(
    const int* __restrict__ rowptr, const int2* __restrict__ eg,
    const float* __restrict__ dinv,
    const float* __restrict__ X1, long bs1,
    const _Float16* __restrict__ Hs,
    unsigned short* __restrict__ Ah, unsigned short* __restrict__ Al) {
  if (blockIdx.y == 0)
    spmm_body_f32<64>(rowptr, eg, dinv, X1, bs1, 0, 192, Ah, Al);
  else
    spmm_body_f16<128>(rowptr, eg, dinv, Hs, (long)N_NODES * H, 64, 192, Ah, Al);
}

// layer 1: pass0 = h0 (fp16), pass1 = h1 (fp16)
__global__ __launch_bounds__(256) void k_spmm_l1(
    const int* __restrict__ rowptr, const int2* __restrict__ eg,
    const float* __restrict__ dinv,
    const _Float16* __restrict__ H0, const _Float16* __restrict__ H1,
    unsigned short* __restrict__ Ah, unsigned short* __restrict__ Al) {
  if (blockIdx.y == 0)
    spmm_body_f16<128>(rowptr, eg, dinv, H0, (long)N_NODES * H, 0, 256, Ah, Al);
  else
    spmm_body_f16<128>(rowptr, eg, dinv, H1, (long)N_NODES * H, 128, 256, Ah, Al);
}

// ---------------- MFMA GEMM (split-bf16, 3-term) + fused LSTM ----------------
// block = 4 waves = one 64-row tile x all 512 cols; h written as fp16.
template<int K>
__global__ __launch_bounds__(256, 2) void k_gemm_lstm(
    const unsigned short* __restrict__ Ah, const unsigned short* __restrict__ Al,
    const unsigned short* __restrict__ Bp, const float* __restrict__ bias,
    _Float16* __restrict__ hbuf, float* __restrict__ cbuf,
    float* __restrict__ out2, int t) {
  constexpr int KB = K / 32;
  __shared__ __align__(16) unsigned short At[8 * KB * 64 * 8];  // 48/64 KB
  int tid  = threadIdx.x;
  int j    = blockIdx.x;                          // 512 blocks
  int mblk = (j & 7) * 64 + (j >> 3);             // XCD-align with producer batch
  int m0   = mblk * 64;
  int lane = tid & 63;
  int w    = tid >> 6;

  constexpr int NCH = 8 * KB * 64;
  #pragma unroll
  for (int it = 0; it < NCH / 256; ++it) {
    int chunk = it * 256 + tid;
    int cl = chunk & 63;
    int t1 = chunk >> 6;
    int kb = t1 % KB;
    int pm = t1 / KB;
    int mt = pm & 3, pl = pm >> 2;
    const unsigned short* sp = (pl ? Al : Ah)
        + (long)(m0 + mt * 16 + (cl & 15)) * K + kb * 32 + (cl >> 4) * 8;
    long long q0 = __builtin_nontemporal_load((const long long*)sp);
    long long q1 = __builtin_nontemporal_load((const long long*)sp + 1);
    *(long long*)(At + (long)chunk * 8)     = q0;
    *(long long*)(At + (long)chunk * 8 + 4) = q1;
  }
  __syncthreads();

  int fgb = w * 2;
  int l15 = lane & 15, lq = lane >> 4;

  #pragma unroll
  for (int ff = 0; ff < 2; ++ff) {
    const unsigned short* bb  = Bp + (long)((fgb + ff) * 4) * 512 + lane * 8;
    const unsigned short* blp = bb + (long)K * 512;

    f32x4 acc[4][4];
    #pragma unroll
    for (int mt = 0; mt < 4; ++mt)
      #pragma unroll
      for (int gt = 0; gt < 4; ++gt)
        acc[mt][gt] = (f32x4){0.f, 0.f, 0.f, 0.f};

    for (int kb = 0; kb < KB; ++kb) {
      bf16x8 AH_[4], AL_[4];
      #pragma unroll
      for (int mt = 0; mt < 4; ++mt) {
        AH_[mt] = *(const bf16x8*)(At + (((mt)     * KB + kb) * 64 + lane) * 8);
        AL_[mt] = *(const bf16x8*)(At + (((4 + mt) * KB + kb) * 64 + lane) * 8);
      }
      bf16x8 BH[4], BL[4];
      #pragma unroll
      for (int gt = 0; gt < 4; ++gt) {
        BH[gt] = *(const bf16x8*)(bb  + ((long)kb * 32 + gt) * 512);
        BL[gt] = *(const bf16x8*)(blp + ((long)kb * 32 + gt) * 512);
      }
      #pragma unroll
      for (int gt = 0; gt < 4; ++gt) {
        #pragma unroll
        for (int mt = 0; mt < 4; ++mt) {
          acc[mt][gt] = __builtin_amdgcn_mfma_f32_16x16x32_bf16(AH_[mt], BH[gt], acc[mt][gt], 0, 0, 0);
          acc[mt][gt] = __builtin_amdgcn_mfma_f32_16x16x32_bf16(AL_[mt], BH[gt], acc[mt][gt], 0, 0, 0);
          acc[mt][gt] = __builtin_amdgcn_mfma_f32_16x16x32_bf16(AH_[mt], BL[gt], acc[mt][gt], 0, 0, 0);
        }
      }
    }

    int f = (fgb + ff) * 16 + l15;
    float bi = bias[f], bff = bias[128 + f], bo = bias[256 + f], bg = bias[384 + f];
    #pragma unroll
    for (int mt = 0; mt < 4; ++mt) {
      #pragma unroll
      for (int r = 0; r < 4; ++r) {
        int m = m0 + mt * 16 + lq * 4 + r;
        float vi = 1.0f / (1.0f + __expf(-(acc[mt][0][r] + bi)));
        float vf = 1.0f / (1.0f + __expf(-(acc[mt][1][r] + bff)));
        float vo = 1.0f / (1.0f + __expf(-(acc[mt][2][r] + bo)));
        float vg = tanhf(acc[mt][3][r] + bg);
        long idx = (long)m * H + f;
        float cn = vf * cbuf[idx] + vi * vg;
        float hn = vo * tanhf(cn);
        cbuf[idx] = cn;
        hbuf[idx] = (_Float16)hn;
        if (out2) {
          int bb2 = m >> 12, nn = m & (N_NODES - 1);
          __builtin_nontemporal_store(hn,
              &out2[(((long)bb2 * T + t) * N_NODES + nn) * H + f]);
        }
      }
    }
  }
}

// ---------------- launch ----------------

extern "C" void kernel_launch(void* const* d_in, const int* in_sizes, int n_in,
                              void* d_out, int out_size, void* d_ws, size_t ws_size,
                              hipStream_t stream) {
  const float* x  = (const float*)d_in[0];
  const float* W0 = (const float*)d_in[1];
  const float* b0 = (const float*)d_in[2];
  const float* W1 = (const float*)d_in[3];
  const float* b1 = (const float*)d_in[4];
  const int*   ei = (const int*)d_in[5];
  const int* srcp = ei;
  const int* dstp = ei + N_EDGES;
  float* out = (float*)d_out;

  char* p = (char*)d_ws;
  auto alloc = [&](size_t bytes) {
    char* r = p;
    p += (bytes + 255) & ~(size_t)255;
    return r;
  };
  int*   cnt    = (int*)  alloc(N_NODES * 4);
  int*   fill   = (int*)  alloc(N_NODES * 4);
  float* dinv   = (float*)alloc(N_NODES * 4);
  int*   rowptr = (int*)  alloc((N_NODES + 1) * 4);
  int2*  eg     = (int2*) alloc((size_t)N_EDGES * 8);
  float* cc     = (float*)alloc((size_t)2 * M * H * 4);      // c0,c1 fp32
  _Float16* hh  = (_Float16*)alloc((size_t)2 * M * H * 2);   // h0,h1 fp16
  unsigned short* Ah  = (unsigned short*)alloc((size_t)M * 256 * 2);
  unsigned short* Al  = (unsigned short*)alloc((size_t)M * 256 * 2);
  unsigned short* Bp0 = (unsigned short*)alloc((size_t)192 * 512 * 2 * 2);
  unsigned short* Bp1 = (unsigned short*)alloc((size_t)256 * 512 * 2 * 2);
  float*    c0 = cc;
  float*    c1 = cc + (size_t)M * H;
  _Float16* h0 = hh;
  _Float16* h1 = hh + (size_t)M * H;

  hipMemsetAsync(cnt,  0, N_NODES * 4, stream);
  hipMemsetAsync(fill, 0, N_NODES * 4, stream);
  hipMemsetAsync(cc,   0, (size_t)2 * M * H * 4, stream);
  hipMemsetAsync(hh,   0, (size_t)2 * M * H * 2, stream);

  k_count<<<N_EDGES / 256, 256, 0, stream>>>(dstp, cnt);
  k_dinv <<<N_NODES / 256, 256, 0, stream>>>(cnt, dinv);
  k_scan <<<1, 1024, 0, stream>>>(cnt, rowptr);
  k_fill <<<N_EDGES / 256, 256, 0, stream>>>(srcp, dstp, dinv, rowptr, fill, eg);
  k_pack <<<(192 * 64 + 255) / 256, 256, 0, stream>>>(W0, Bp0, 192);
  k_pack <<<(256 * 64 + 255) / 256, 256, 0, stream>>>(W1, Bp1, 256);

  for (int t = 0; t < T; ++t) {
    // layer 0: A = A_hat @ [x_t | h0]   (K = 192)
    k_spmm_l0<<<dim3(M / 4, 2), 256, 0, stream>>>(rowptr, eg, dinv,
        x + (size_t)t * N_NODES * D_INF, (long)T * N_NODES * D_INF,
        h0, Ah, Al);
    k_gemm_lstm<192><<<512, 256, 0, stream>>>(Ah, Al, Bp0, b0, h0, c0, nullptr, t);
    // layer 1: A = A_hat @ [h0_t | h1]  (K = 256)
    k_spmm_l1<<<dim3(M / 4, 2), 256, 0, stream>>>(rowptr, eg, dinv,
        h0, h1, Ah, Al);
    k_gemm_lstm<256><<<512, 256, 0, stream>>>(Ah, Al, Bp1, b1, h1, c1, out, t);
  }
}

// Round 8
// 1193.065 us; speedup vs baseline: 1.3133x; 1.1665x over previous
//
#include <hip/hip_runtime.h>
#include <hip/hip_fp16.h>
#include <math.h>

constexpr int N_NODES = 4096;
constexpr int N_EDGES = 65536;
constexpr int D_INF   = 64;
constexpr int H       = 128;
constexpr int T       = 8;
constexpr int B       = 8;
constexpr int M       = B * N_NODES;   // 32768 rows per GEMM

typedef __attribute__((ext_vector_type(8))) short bf16x8;
typedef __attribute__((ext_vector_type(4))) float f32x4;
typedef __attribute__((ext_vector_type(8))) _Float16 f16x8;

__device__ inline unsigned short f2bf(float x) {
  unsigned int u = __float_as_uint(x);
  unsigned int r = (u + 0x7fffu + ((u >> 16) & 1u)) >> 16;
  return (unsigned short)r;
}
__device__ inline float bf2f(unsigned short b) {
  return __uint_as_float((unsigned int)b << 16);
}

// ---------------- CSR build ----------------

__global__ void k_count(const int* __restrict__ dst, int* __restrict__ cnt) {
  int e = blockIdx.x * blockDim.x + threadIdx.x;
  if (e < N_EDGES) atomicAdd(&cnt[dst[e]], 1);
}

__global__ void k_dinv(const int* __restrict__ cnt, float* __restrict__ dinv) {
  int n = blockIdx.x * blockDim.x + threadIdx.x;
  if (n < N_NODES) dinv[n] = 1.0f / sqrtf((float)cnt[n] + 2.0f);
}

__global__ void k_scan(const int* __restrict__ cnt, int* __restrict__ rowptr) {
  __shared__ int sums[1024];
  int t = threadIdx.x;
  int v0 = cnt[4*t+0], v1 = cnt[4*t+1], v2 = cnt[4*t+2], v3 = cnt[4*t+3];
  int s0 = v0, s1 = s0 + v1, s2 = s1 + v2, s3 = s2 + v3;
  sums[t] = s3;
  __syncthreads();
  for (int off = 1; off < 1024; off <<= 1) {
    int x = (t >= off) ? sums[t - off] : 0;
    __syncthreads();
    sums[t] += x;
    __syncthreads();
  }
  int base = (t > 0) ? sums[t - 1] : 0;
  if (t == 0) rowptr[0] = 0;
  rowptr[4*t+1] = base + s0;
  rowptr[4*t+2] = base + s1;
  rowptr[4*t+3] = base + s2;
  rowptr[4*t+4] = base + s3;
}

__global__ void k_fill(const int* __restrict__ src, const int* __restrict__ dst,
                       const float* __restrict__ dinv, const int* __restrict__ rowptr,
                       int* __restrict__ fill, int2* __restrict__ eg) {
  int e = blockIdx.x * blockDim.x + threadIdx.x;
  if (e >= N_EDGES) return;
  int s = src[e], d = dst[e];
  int p = rowptr[d] + atomicAdd(&fill[d], 1);
  eg[p] = make_int2(s, __float_as_int(dinv[s] * dinv[d]));
}

// ---------------- W pack: gate-interleaved cols + MFMA fragment order + hi/lo ----
__global__ void k_pack(const float* __restrict__ W, unsigned short* __restrict__ Bp,
                       int K) {
  int tid = blockIdx.x * 256 + threadIdx.x;
  if (tid >= K * 64) return;
  int lane = tid & 63;
  int ntg  = (tid >> 6) & 31;
  int kb   = tid >> 11;
  int gate = ntg & 3, fg = ntg >> 2;
  int corig = gate * 128 + fg * 16 + (lane & 15);
  int k0 = kb * 32 + (lane >> 4) * 8;
  long obase = ((long)(kb * 32 + ntg) * 64 + lane) * 8;
  long plane = (long)K * 512;
  #pragma unroll
  for (int j = 0; j < 8; ++j) {
    float v = W[(long)(k0 + j) * 512 + corig];
    unsigned short h = f2bf(v);
    Bp[obase + j]         = h;
    Bp[plane + obase + j] = f2bf(v - bf2f(h));
  }
}

// ---------------- fused: gather (SpMM) -> LDS fragments -> MFMA GEMM -> LSTM ----
// Block = 4 waves = 64 rows (one batch's 64 nodes) x all 512 gate cols.
// Phase 1: per 16-lane node group, iterate CSR edges once, gathering BOTH
//   source planes; accumulate fp32; write split-bf16 straight into the
//   fragment-layout LDS (At) the MFMA loop reads. No global A intermediate.
// Phase 2: split-bf16 3-term MFMA + in-register LSTM epilogue.
// h is ping-pong buffered across timesteps (gather reads old, epilogue
// writes new) to avoid cross-block RAW races. c is owner-block-only.
template<int K, bool L0>
__global__ __launch_bounds__(256, 2) void k_fused(
    const int* __restrict__ rowptr, const int2* __restrict__ eg,
    const float* __restrict__ dinv,
    const float* __restrict__ X32,      // L0 only: x_t base (batch stride T*N*D)
    const _Float16* __restrict__ PH0,   // L0: h0_old ; L1: h0_new
    const _Float16* __restrict__ PH1,   // L1: h1_old
    const unsigned short* __restrict__ Bp, const float* __restrict__ bias,
    _Float16* __restrict__ hout, float* __restrict__ cbuf,
    float* __restrict__ out2, int t) {
  constexpr int KB = K / 32;
  __shared__ __align__(16) unsigned short At[8 * KB * 64 * 8];  // 48/64 KB
  int tid  = threadIdx.x;
  int lane = tid & 63;
  int w    = tid >> 6;
  int j    = blockIdx.x;                 // 512 blocks, 512%8==0 -> bijective swizzle
  int b    = j & 7;                      // batch == XCD (round-robin heuristic)
  int n0   = (j >> 3) * 64;              // node tile within batch
  int m0   = (b * 64 + (j >> 3)) * 64;   // row tile in [0, M)
  int g    = lane >> 4, l = lane & 15;
  int c4   = l * 4, c8 = l * 8;

  // ---- phase 1: gather both planes, emit LDS fragments ----
  const float*    Ax   = L0 ? (X32 + (long)b * ((long)T * N_NODES * D_INF)) : nullptr;
  const _Float16* Ah_p = L0 ? nullptr : (PH0 + (long)b * N_NODES * H);
  const _Float16* Bh_p = (L0 ? PH0 : PH1) + (long)b * N_NODES * H;
  constexpr int kbB0 = (L0 ? 64 : 128) >> 5;       // plane B k-offset (chunks)
  int lane2f = 16 * (l & 3);
  int kbB    = kbB0 + (c8 >> 5);
  int kbA16  = c8 >> 5;
  int kbA32  = c4 >> 5;
  int subA32 = (l & 7) >> 1;
  int j0A32  = (l & 1) * 4;

  for (int nd = 0; nd < 4; ++nd) {
    int r  = (w << 4) + (g << 2) + nd;   // row in tile, 0..63
    int n  = n0 + r;
    int rs = rowptr[n], re = rowptr[n + 1];
    float accA[8] = {0.f,0.f,0.f,0.f,0.f,0.f,0.f,0.f};
    float accB[8] = {0.f,0.f,0.f,0.f,0.f,0.f,0.f,0.f};
    int e = rs;
    for (; e + 1 < re; e += 2) {
      long long r0 = __builtin_nontemporal_load((const long long*)&eg[e]);
      long long r1 = __builtin_nontemporal_load((const long long*)&eg[e + 1]);
      int ci0 = (int)r0, ci1 = (int)r1;
      float w0 = __int_as_float((int)(r0 >> 32));
      float w1 = __int_as_float((int)(r1 >> 32));
      if constexpr (L0) {
        f32x4 a0 = *(const f32x4*)(Ax + (long)ci0 * D_INF + c4);
        f32x4 a1 = *(const f32x4*)(Ax + (long)ci1 * D_INF + c4);
        #pragma unroll
        for (int q = 0; q < 4; ++q) accA[q] += w0 * a0[q] + w1 * a1[q];
      } else {
        f16x8 a0 = *(const f16x8*)(Ah_p + (long)ci0 * H + c8);
        f16x8 a1 = *(const f16x8*)(Ah_p + (long)ci1 * H + c8);
        #pragma unroll
        for (int q = 0; q < 8; ++q) accA[q] += w0 * (float)a0[q] + w1 * (float)a1[q];
      }
      f16x8 b0 = *(const f16x8*)(Bh_p + (long)ci0 * H + c8);
      f16x8 b1 = *(const f16x8*)(Bh_p + (long)ci1 * H + c8);
      #pragma unroll
      for (int q = 0; q < 8; ++q) accB[q] += w0 * (float)b0[q] + w1 * (float)b1[q];
    }
    if (e < re) {
      long long r0 = __builtin_nontemporal_load((const long long*)&eg[e]);
      int ci0 = (int)r0;
      float w0 = __int_as_float((int)(r0 >> 32));
      if constexpr (L0) {
        f32x4 a0 = *(const f32x4*)(Ax + (long)ci0 * D_INF + c4);
        #pragma unroll
        for (int q = 0; q < 4; ++q) accA[q] += w0 * a0[q];
      } else {
        f16x8 a0 = *(const f16x8*)(Ah_p + (long)ci0 * H + c8);
        #pragma unroll
        for (int q = 0; q < 8; ++q) accA[q] += w0 * (float)a0[q];
      }
      f16x8 b0 = *(const f16x8*)(Bh_p + (long)ci0 * H + c8);
      #pragma unroll
      for (int q = 0; q < 8; ++q) accB[q] += w0 * (float)b0[q];
    }
    float dn = dinv[n];
    float sw = 2.0f * dn * dn;
    if constexpr (L0) {
      f32x4 a = *(const f32x4*)(Ax + (long)n * D_INF + c4);
      #pragma unroll
      for (int q = 0; q < 4; ++q) accA[q] += sw * a[q];
    } else {
      f16x8 a = *(const f16x8*)(Ah_p + (long)n * H + c8);
      #pragma unroll
      for (int q = 0; q < 8; ++q) accA[q] += sw * (float)a[q];
    }
    {
      f16x8 v = *(const f16x8*)(Bh_p + (long)n * H + c8);
      #pragma unroll
      for (int q = 0; q < 8; ++q) accB[q] += sw * (float)v[q];
    }

    int mt    = r >> 4;
    int lane2 = (r & 15) + lane2f;
    // plane B: full 8-feat chunk
    {
      bf16x8 hv, lv;
      #pragma unroll
      for (int q = 0; q < 8; ++q) {
        unsigned short hs = f2bf(accB[q]);
        hv[q] = (short)hs;
        lv[q] = (short)f2bf(accB[q] - bf2f(hs));
      }
      *(bf16x8*)(At + (((mt)     * KB + kbB) * 64 + lane2) * 8) = hv;
      *(bf16x8*)(At + (((4 + mt) * KB + kbB) * 64 + lane2) * 8) = lv;
    }
    // plane A
    if constexpr (L0) {
      unsigned long long hv = 0ull, lv = 0ull;
      #pragma unroll
      for (int q = 0; q < 4; ++q) {
        unsigned short hs = f2bf(accA[q]);
        unsigned short ls = f2bf(accA[q] - bf2f(hs));
        hv |= (unsigned long long)hs << (16 * q);
        lv |= (unsigned long long)ls << (16 * q);
      }
      int lA = (r & 15) + 16 * subA32;
      *(unsigned long long*)(At + (((mt)     * KB + kbA32) * 64 + lA) * 8 + j0A32) = hv;
      *(unsigned long long*)(At + (((4 + mt) * KB + kbA32) * 64 + lA) * 8 + j0A32) = lv;
    } else {
      bf16x8 hv, lv;
      #pragma unroll
      for (int q = 0; q < 8; ++q) {
        unsigned short hs = f2bf(accA[q]);
        hv[q] = (short)hs;
        lv[q] = (short)f2bf(accA[q] - bf2f(hs));
      }
      *(bf16x8*)(At + (((mt)     * KB + kbA16) * 64 + lane2) * 8) = hv;
      *(bf16x8*)(At + (((4 + mt) * KB + kbA16) * 64 + lane2) * 8) = lv;
    }
  }
  __syncthreads();

  // ---- phase 2: split-bf16 3-term MFMA + LSTM epilogue ----
  int fgb = w * 2;
  int l15 = lane & 15, lq = lane >> 4;

  #pragma unroll
  for (int ff = 0; ff < 2; ++ff) {
    const unsigned short* bb  = Bp + (long)((fgb + ff) * 4) * 512 + lane * 8;
    const unsigned short* blp = bb + (long)K * 512;

    f32x4 acc[4][4];
    #pragma unroll
    for (int mt = 0; mt < 4; ++mt)
      #pragma unroll
      for (int gt = 0; gt < 4; ++gt)
        acc[mt][gt] = (f32x4){0.f, 0.f, 0.f, 0.f};

    for (int kb = 0; kb < KB; ++kb) {
      bf16x8 AH_[4], AL_[4];
      #pragma unroll
      for (int mt = 0; mt < 4; ++mt) {
        AH_[mt] = *(const bf16x8*)(At + (((mt)     * KB + kb) * 64 + lane) * 8);
        AL_[mt] = *(const bf16x8*)(At + (((4 + mt) * KB + kb) * 64 + lane) * 8);
      }
      bf16x8 BH[4], BL[4];
      #pragma unroll
      for (int gt = 0; gt < 4; ++gt) {
        BH[gt] = *(const bf16x8*)(bb  + ((long)kb * 32 + gt) * 512);
        BL[gt] = *(const bf16x8*)(blp + ((long)kb * 32 + gt) * 512);
      }
      #pragma unroll
      for (int gt = 0; gt < 4; ++gt) {
        #pragma unroll
        for (int mt = 0; mt < 4; ++mt) {
          acc[mt][gt] = __builtin_amdgcn_mfma_f32_16x16x32_bf16(AH_[mt], BH[gt], acc[mt][gt], 0, 0, 0);
          acc[mt][gt] = __builtin_amdgcn_mfma_f32_16x16x32_bf16(AL_[mt], BH[gt], acc[mt][gt], 0, 0, 0);
          acc[mt][gt] = __builtin_amdgcn_mfma_f32_16x16x32_bf16(AH_[mt], BL[gt], acc[mt][gt], 0, 0, 0);
        }
      }
    }

    int f = (fgb + ff) * 16 + l15;
    float bi = bias[f], bff = bias[128 + f], bo = bias[256 + f], bg = bias[384 + f];
    #pragma unroll
    for (int mt = 0; mt < 4; ++mt) {
      #pragma unroll
      for (int r = 0; r < 4; ++r) {
        int m = m0 + mt * 16 + lq * 4 + r;
        float vi = 1.0f / (1.0f + __expf(-(acc[mt][0][r] + bi)));
        float vf = 1.0f / (1.0f + __expf(-(acc[mt][1][r] + bff)));
        float vo = 1.0f / (1.0f + __expf(-(acc[mt][2][r] + bo)));
        float vg = tanhf(acc[mt][3][r] + bg);
        long idx = (long)m * H + f;
        float cn = vf * cbuf[idx] + vi * vg;
        float hn = vo * tanhf(cn);
        cbuf[idx] = cn;
        hout[idx] = (_Float16)hn;
        if (out2) {
          int bb2 = m >> 12, nn = m & (N_NODES - 1);
          __builtin_nontemporal_store(hn,
              &out2[(((long)bb2 * T + t) * N_NODES + nn) * H + f]);
        }
      }
    }
  }
}

// ---------------- launch ----------------

extern "C" void kernel_launch(void* const* d_in, const int* in_sizes, int n_in,
                              void* d_out, int out_size, void* d_ws, size_t ws_size,
                              hipStream_t stream) {
  const float* x  = (const float*)d_in[0];
  const float* W0 = (const float*)d_in[1];
  const float* b0 = (const float*)d_in[2];
  const float* W1 = (const float*)d_in[3];
  const float* b1 = (const float*)d_in[4];
  const int*   ei = (const int*)d_in[5];
  const int* srcp = ei;
  const int* dstp = ei + N_EDGES;
  float* out = (float*)d_out;

  char* p = (char*)d_ws;
  auto alloc = [&](size_t bytes) {
    char* r = p;
    p += (bytes + 255) & ~(size_t)255;
    return r;
  };
  int*   cnt    = (int*)  alloc(N_NODES * 4);
  int*   fill   = (int*)  alloc(N_NODES * 4);
  float* dinv   = (float*)alloc(N_NODES * 4);
  int*   rowptr = (int*)  alloc((N_NODES + 1) * 4);
  int2*  eg     = (int2*) alloc((size_t)N_EDGES * 8);
  float* cc     = (float*)alloc((size_t)2 * M * H * 4);      // c0,c1 fp32
  _Float16* hh  = (_Float16*)alloc((size_t)4 * M * H * 2);   // h0 x2, h1 x2 (ping-pong)
  unsigned short* Bp0 = (unsigned short*)alloc((size_t)192 * 512 * 2 * 2);
  unsigned short* Bp1 = (unsigned short*)alloc((size_t)256 * 512 * 2 * 2);
  float*    c0  = cc;
  float*    c1  = cc + (size_t)M * H;
  _Float16* h0a = hh;
  _Float16* h0b = hh + (size_t)M * H;
  _Float16* h1a = hh + (size_t)2 * M * H;
  _Float16* h1b = hh + (size_t)3 * M * H;

  hipMemsetAsync(cnt,  0, N_NODES * 4, stream);
  hipMemsetAsync(fill, 0, N_NODES * 4, stream);
  hipMemsetAsync(cc,   0, (size_t)2 * M * H * 4, stream);
  hipMemsetAsync(hh,   0, (size_t)4 * M * H * 2, stream);

  k_count<<<N_EDGES / 256, 256, 0, stream>>>(dstp, cnt);
  k_dinv <<<N_NODES / 256, 256, 0, stream>>>(cnt, dinv);
  k_scan <<<1, 1024, 0, stream>>>(cnt, rowptr);
  k_fill <<<N_EDGES / 256, 256, 0, stream>>>(srcp, dstp, dinv, rowptr, fill, eg);
  k_pack <<<(192 * 64 + 255) / 256, 256, 0, stream>>>(W0, Bp0, 192);
  k_pack <<<(256 * 64 + 255) / 256, 256, 0, stream>>>(W1, Bp1, 256);

  for (int t = 0; t < T; ++t) {
    const _Float16* h0r = (t & 1) ? h0b : h0a;
    _Float16*       h0w = (t & 1) ? h0a : h0b;
    const _Float16* h1r = (t & 1) ? h1b : h1a;
    _Float16*       h1w = (t & 1) ? h1a : h1b;
    // layer 0: gather [x_t | h0_old] -> gates -> h0_new, c0
    k_fused<192, true><<<512, 256, 0, stream>>>(rowptr, eg, dinv,
        x + (size_t)t * N_NODES * D_INF, h0r, nullptr,
        Bp0, b0, h0w, c0, nullptr, t);
    // layer 1: gather [h0_new | h1_old] -> gates -> h1_new, c1, out
    k_fused<256, false><<<512, 256, 0, stream>>>(rowptr, eg, dinv,
        nullptr, h0w, h1r,
        Bp1, b1, h1w, c1, out, t);
  }
}

// Round 9
// 961.461 us; speedup vs baseline: 1.6296x; 1.2409x over previous
//
#include <hip/hip_runtime.h>
#include <hip/hip_fp16.h>
#include <math.h>

constexpr int N_NODES = 4096;
constexpr int N_EDGES = 65536;
constexpr int D_INF   = 64;
constexpr int H       = 128;
constexpr int T       = 8;
constexpr int B       = 8;
constexpr int M       = B * N_NODES;   // 32768 rows per GEMM

typedef __attribute__((ext_vector_type(8))) short bf16x8;
typedef __attribute__((ext_vector_type(4))) float f32x4;
typedef __attribute__((ext_vector_type(8))) _Float16 f16x8;

__device__ inline unsigned short f2bf(float x) {
  unsigned int u = __float_as_uint(x);
  unsigned int r = (u + 0x7fffu + ((u >> 16) & 1u)) >> 16;
  return (unsigned short)r;
}
__device__ inline float bf2f(unsigned short b) {
  return __uint_as_float((unsigned int)b << 16);
}
// LDS bank swizzle: XOR byte bits 8-10 into bank bits 4-6 (short-index form).
__device__ __forceinline__ int swz(int s) { return s ^ (((s >> 7) & 7) << 3); }

// ---------------- CSR build ----------------

__global__ void k_count(const int* __restrict__ dst, int* __restrict__ cnt) {
  int e = blockIdx.x * blockDim.x + threadIdx.x;
  if (e < N_EDGES) atomicAdd(&cnt[dst[e]], 1);
}

__global__ void k_dinv(const int* __restrict__ cnt, float* __restrict__ dinv) {
  int n = blockIdx.x * blockDim.x + threadIdx.x;
  if (n < N_NODES) dinv[n] = 1.0f / sqrtf((float)cnt[n] + 2.0f);
}

__global__ void k_scan(const int* __restrict__ cnt, int* __restrict__ rowptr) {
  __shared__ int sums[1024];
  int t = threadIdx.x;
  int v0 = cnt[4*t+0], v1 = cnt[4*t+1], v2 = cnt[4*t+2], v3 = cnt[4*t+3];
  int s0 = v0, s1 = s0 + v1, s2 = s1 + v2, s3 = s2 + v3;
  sums[t] = s3;
  __syncthreads();
  for (int off = 1; off < 1024; off <<= 1) {
    int x = (t >= off) ? sums[t - off] : 0;
    __syncthreads();
    sums[t] += x;
    __syncthreads();
  }
  int base = (t > 0) ? sums[t - 1] : 0;
  if (t == 0) rowptr[0] = 0;
  rowptr[4*t+1] = base + s0;
  rowptr[4*t+2] = base + s1;
  rowptr[4*t+3] = base + s2;
  rowptr[4*t+4] = base + s3;
}

__global__ void k_fill(const int* __restrict__ src, const int* __restrict__ dst,
                       const float* __restrict__ dinv, const int* __restrict__ rowptr,
                       int* __restrict__ fill, int2* __restrict__ eg) {
  int e = blockIdx.x * blockDim.x + threadIdx.x;
  if (e >= N_EDGES) return;
  int s = src[e], d = dst[e];
  int p = rowptr[d] + atomicAdd(&fill[d], 1);
  eg[p] = make_int2(s, __float_as_int(dinv[s] * dinv[d]));
}

// ---------------- W pack: gate-interleaved cols + MFMA fragment order + hi/lo ----
__global__ void k_pack(const float* __restrict__ W, unsigned short* __restrict__ Bp,
                       int K) {
  int tid = blockIdx.x * 256 + threadIdx.x;
  if (tid >= K * 64) return;
  int lane = tid & 63;
  int ntg  = (tid >> 6) & 31;
  int kb   = tid >> 11;
  int gate = ntg & 3, fg = ntg >> 2;
  int corig = gate * 128 + fg * 16 + (lane & 15);
  int k0 = kb * 32 + (lane >> 4) * 8;
  long obase = ((long)(kb * 32 + ntg) * 64 + lane) * 8;
  long plane = (long)K * 512;
  #pragma unroll
  for (int j = 0; j < 8; ++j) {
    float v = W[(long)(k0 + j) * 512 + corig];
    unsigned short h = f2bf(v);
    Bp[obase + j]         = h;
    Bp[plane + obase + j] = f2bf(v - bf2f(h));
  }
}

// ---------------- fused: gather (SpMM) -> swizzled LDS fragments -> MFMA -> LSTM --
// Block = 8 waves (512 thr) = 64 rows (one batch's 64 nodes) x all 512 gate cols.
// Phase 1: 32 groups of 16 lanes; each group gathers 2 nodes' edges for BOTH
//   source planes, writes split-bf16 into bank-swizzled fragment LDS.
// Phase 2: each wave computes ONE 16-feature group (all 4 gates, 64 rows).
template<int K, bool L0>
__global__ __launch_bounds__(512, 4) void k_fused(
    const int* __restrict__ rowptr, const int2* __restrict__ eg,
    const float* __restrict__ dinv,
    const float* __restrict__ X32,      // L0 only: x_t base (batch stride T*N*D)
    const _Float16* __restrict__ PH0,   // L0: h0_old ; L1: h0_new
    const _Float16* __restrict__ PH1,   // L1: h1_old
    const unsigned short* __restrict__ Bp, const float* __restrict__ bias,
    _Float16* __restrict__ hout, float* __restrict__ cbuf,
    float* __restrict__ out2, int t) {
  constexpr int KB = K / 32;
  __shared__ __align__(16) unsigned short At[8 * KB * 64 * 8];  // 48/64 KB
  int tid  = threadIdx.x;
  int lane = tid & 63;
  int w    = tid >> 6;                   // 0..7
  int j    = blockIdx.x;                 // 512 blocks
  int b    = j & 7;                      // batch == XCD round-robin
  int n0   = (j >> 3) * 64;
  int m0   = (b * 64 + (j >> 3)) * 64;
  int g    = lane >> 4, l = lane & 15;
  int c4   = l * 4, c8 = l * 8;

  // ---- phase 1: gather both planes, emit swizzled LDS fragments ----
  const float*    Ax   = L0 ? (X32 + (long)b * ((long)T * N_NODES * D_INF)) : nullptr;
  const _Float16* Ah_p = L0 ? nullptr : (PH0 + (long)b * N_NODES * H);
  const _Float16* Bh_p = (L0 ? PH0 : PH1) + (long)b * N_NODES * H;
  constexpr int kbB0 = (L0 ? 64 : 128) >> 5;
  int lane2f = 16 * (l & 3);
  int kbB    = kbB0 + (c8 >> 5);
  int kbA16  = c8 >> 5;
  int kbA32  = c4 >> 5;
  int subA32 = (l & 7) >> 1;
  int j0A32  = (l & 1) * 4;

  #pragma unroll
  for (int nd = 0; nd < 2; ++nd) {
    int r  = (w << 3) + (g << 1) + nd;   // row in tile, 0..63
    int n  = n0 + r;
    int rs = rowptr[n], re = rowptr[n + 1];
    float accA[8] = {0.f,0.f,0.f,0.f,0.f,0.f,0.f,0.f};
    float accB[8] = {0.f,0.f,0.f,0.f,0.f,0.f,0.f,0.f};
    int e = rs;
    for (; e + 1 < re; e += 2) {
      long long r0 = __builtin_nontemporal_load((const long long*)&eg[e]);
      long long r1 = __builtin_nontemporal_load((const long long*)&eg[e + 1]);
      int ci0 = (int)r0, ci1 = (int)r1;
      float w0 = __int_as_float((int)(r0 >> 32));
      float w1 = __int_as_float((int)(r1 >> 32));
      if constexpr (L0) {
        f32x4 a0 = *(const f32x4*)(Ax + (long)ci0 * D_INF + c4);
        f32x4 a1 = *(const f32x4*)(Ax + (long)ci1 * D_INF + c4);
        #pragma unroll
        for (int q = 0; q < 4; ++q) accA[q] += w0 * a0[q] + w1 * a1[q];
      } else {
        f16x8 a0 = *(const f16x8*)(Ah_p + (long)ci0 * H + c8);
        f16x8 a1 = *(const f16x8*)(Ah_p + (long)ci1 * H + c8);
        #pragma unroll
        for (int q = 0; q < 8; ++q) accA[q] += w0 * (float)a0[q] + w1 * (float)a1[q];
      }
      f16x8 b0 = *(const f16x8*)(Bh_p + (long)ci0 * H + c8);
      f16x8 b1 = *(const f16x8*)(Bh_p + (long)ci1 * H + c8);
      #pragma unroll
      for (int q = 0; q < 8; ++q) accB[q] += w0 * (float)b0[q] + w1 * (float)b1[q];
    }
    if (e < re) {
      long long r0 = __builtin_nontemporal_load((const long long*)&eg[e]);
      int ci0 = (int)r0;
      float w0 = __int_as_float((int)(r0 >> 32));
      if constexpr (L0) {
        f32x4 a0 = *(const f32x4*)(Ax + (long)ci0 * D_INF + c4);
        #pragma unroll
        for (int q = 0; q < 4; ++q) accA[q] += w0 * a0[q];
      } else {
        f16x8 a0 = *(const f16x8*)(Ah_p + (long)ci0 * H + c8);
        #pragma unroll
        for (int q = 0; q < 8; ++q) accA[q] += w0 * (float)a0[q];
      }
      f16x8 b0 = *(const f16x8*)(Bh_p + (long)ci0 * H + c8);
      #pragma unroll
      for (int q = 0; q < 8; ++q) accB[q] += w0 * (float)b0[q];
    }
    float dn = dinv[n];
    float sw = 2.0f * dn * dn;
    if constexpr (L0) {
      f32x4 a = *(const f32x4*)(Ax + (long)n * D_INF + c4);
      #pragma unroll
      for (int q = 0; q < 4; ++q) accA[q] += sw * a[q];
    } else {
      f16x8 a = *(const f16x8*)(Ah_p + (long)n * H + c8);
      #pragma unroll
      for (int q = 0; q < 8; ++q) accA[q] += sw * (float)a[q];
    }
    {
      f16x8 v = *(const f16x8*)(Bh_p + (long)n * H + c8);
      #pragma unroll
      for (int q = 0; q < 8; ++q) accB[q] += sw * (float)v[q];
    }

    int mt    = r >> 4;
    int lane2 = (r & 15) + lane2f;
    // plane B: full 8-feat chunk
    {
      bf16x8 hv, lv;
      #pragma unroll
      for (int q = 0; q < 8; ++q) {
        unsigned short hs = f2bf(accB[q]);
        hv[q] = (short)hs;
        lv[q] = (short)f2bf(accB[q] - bf2f(hs));
      }
      *(bf16x8*)(At + swz((((mt)     * KB + kbB) * 64 + lane2) * 8)) = hv;
      *(bf16x8*)(At + swz((((4 + mt) * KB + kbB) * 64 + lane2) * 8)) = lv;
    }
    // plane A
    if constexpr (L0) {
      unsigned long long hv = 0ull, lv = 0ull;
      #pragma unroll
      for (int q = 0; q < 4; ++q) {
        unsigned short hs = f2bf(accA[q]);
        unsigned short ls = f2bf(accA[q] - bf2f(hs));
        hv |= (unsigned long long)hs << (16 * q);
        lv |= (unsigned long long)ls << (16 * q);
      }
      int lA = (r & 15) + 16 * subA32;
      *(unsigned long long*)(At + swz((((mt)     * KB + kbA32) * 64 + lA) * 8 + j0A32)) = hv;
      *(unsigned long long*)(At + swz((((4 + mt) * KB + kbA32) * 64 + lA) * 8 + j0A32)) = lv;
    } else {
      bf16x8 hv, lv;
      #pragma unroll
      for (int q = 0; q < 8; ++q) {
        unsigned short hs = f2bf(accA[q]);
        hv[q] = (short)hs;
        lv[q] = (short)f2bf(accA[q] - bf2f(hs));
      }
      *(bf16x8*)(At + swz((((mt)     * KB + kbA16) * 64 + lane2) * 8)) = hv;
      *(bf16x8*)(At + swz((((4 + mt) * KB + kbA16) * 64 + lane2) * 8)) = lv;
    }
  }
  __syncthreads();

  // ---- phase 2: split-bf16 3-term MFMA + LSTM epilogue (1 fg per wave) ----
  int l15 = lane & 15, lq = lane >> 4;
  const unsigned short* bb  = Bp + (long)(w * 4) * 512 + lane * 8;
  const unsigned short* blp = bb + (long)K * 512;

  f32x4 acc[4][4];
  #pragma unroll
  for (int mt = 0; mt < 4; ++mt)
    #pragma unroll
    for (int gt = 0; gt < 4; ++gt)
      acc[mt][gt] = (f32x4){0.f, 0.f, 0.f, 0.f};

  __builtin_amdgcn_s_setprio(1);
  for (int kb = 0; kb < KB; ++kb) {
    bf16x8 AH_[4], AL_[4];
    #pragma unroll
    for (int mt = 0; mt < 4; ++mt) {
      AH_[mt] = *(const bf16x8*)(At + swz((((mt)     * KB + kb) * 64 + lane) * 8));
      AL_[mt] = *(const bf16x8*)(At + swz((((4 + mt) * KB + kb) * 64 + lane) * 8));
    }
    bf16x8 BH[4], BL[4];
    #pragma unroll
    for (int gt = 0; gt < 4; ++gt) {
      BH[gt] = *(const bf16x8*)(bb  + ((long)kb * 32 + gt) * 512);
      BL[gt] = *(const bf16x8*)(blp + ((long)kb * 32 + gt) * 512);
    }
    #pragma unroll
    for (int gt = 0; gt < 4; ++gt) {
      #pragma unroll
      for (int mt = 0; mt < 4; ++mt) {
        acc[mt][gt] = __builtin_amdgcn_mfma_f32_16x16x32_bf16(AH_[mt], BH[gt], acc[mt][gt], 0, 0, 0);
        acc[mt][gt] = __builtin_amdgcn_mfma_f32_16x16x32_bf16(AL_[mt], BH[gt], acc[mt][gt], 0, 0, 0);
        acc[mt][gt] = __builtin_amdgcn_mfma_f32_16x16x32_bf16(AH_[mt], BL[gt], acc[mt][gt], 0, 0, 0);
      }
    }
  }
  __builtin_amdgcn_s_setprio(0);

  int f = w * 16 + l15;
  float bi = bias[f], bff = bias[128 + f], bo = bias[256 + f], bg = bias[384 + f];
  #pragma unroll
  for (int mt = 0; mt < 4; ++mt) {
    #pragma unroll
    for (int r = 0; r < 4; ++r) {
      int m = m0 + mt * 16 + lq * 4 + r;
      float vi = 1.0f / (1.0f + __expf(-(acc[mt][0][r] + bi)));
      float vf = 1.0f / (1.0f + __expf(-(acc[mt][1][r] + bff)));
      float vo = 1.0f / (1.0f + __expf(-(acc[mt][2][r] + bo)));
      float vg = tanhf(acc[mt][3][r] + bg);
      long idx = (long)m * H + f;
      float cn = vf * cbuf[idx] + vi * vg;
      float hn = vo * tanhf(cn);
      cbuf[idx] = cn;
      hout[idx] = (_Float16)hn;
      if (out2) {
        int bb2 = m >> 12, nn = m & (N_NODES - 1);
        __builtin_nontemporal_store(hn,
            &out2[(((long)bb2 * T + t) * N_NODES + nn) * H + f]);
      }
    }
  }
}

// ---------------- launch ----------------

extern "C" void kernel_launch(void* const* d_in, const int* in_sizes, int n_in,
                              void* d_out, int out_size, void* d_ws, size_t ws_size,
                              hipStream_t stream) {
  const float* x  = (const float*)d_in[0];
  const float* W0 = (const float*)d_in[1];
  const float* b0 = (const float*)d_in[2];
  const float* W1 = (const float*)d_in[3];
  const float* b1 = (const float*)d_in[4];
  const int*   ei = (const int*)d_in[5];
  const int* srcp = ei;
  const int* dstp = ei + N_EDGES;
  float* out = (float*)d_out;

  char* p = (char*)d_ws;
  auto alloc = [&](size_t bytes) {
    char* r = p;
    p += (bytes + 255) & ~(size_t)255;
    return r;
  };
  int*   cnt    = (int*)  alloc(N_NODES * 4);
  int*   fill   = (int*)  alloc(N_NODES * 4);
  float* dinv   = (float*)alloc(N_NODES * 4);
  int*   rowptr = (int*)  alloc((N_NODES + 1) * 4);
  int2*  eg     = (int2*) alloc((size_t)N_EDGES * 8);
  float* cc     = (float*)alloc((size_t)2 * M * H * 4);      // c0,c1 fp32
  _Float16* hh  = (_Float16*)alloc((size_t)4 * M * H * 2);   // h0 x2, h1 x2 (ping-pong)
  unsigned short* Bp0 = (unsigned short*)alloc((size_t)192 * 512 * 2 * 2);
  unsigned short* Bp1 = (unsigned short*)alloc((size_t)256 * 512 * 2 * 2);
  float*    c0  = cc;
  float*    c1  = cc + (size_t)M * H;
  _Float16* h0a = hh;
  _Float16* h0b = hh + (size_t)M * H;
  _Float16* h1a = hh + (size_t)2 * M * H;
  _Float16* h1b = hh + (size_t)3 * M * H;

  hipMemsetAsync(cnt,  0, N_NODES * 4, stream);
  hipMemsetAsync(fill, 0, N_NODES * 4, stream);
  hipMemsetAsync(cc,   0, (size_t)2 * M * H * 4, stream);
  hipMemsetAsync(hh,   0, (size_t)4 * M * H * 2, stream);

  k_count<<<N_EDGES / 256, 256, 0, stream>>>(dstp, cnt);
  k_dinv <<<N_NODES / 256, 256, 0, stream>>>(cnt, dinv);
  k_scan <<<1, 1024, 0, stream>>>(cnt, rowptr);
  k_fill <<<N_EDGES / 256, 256, 0, stream>>>(srcp, dstp, dinv, rowptr, fill, eg);
  k_pack <<<(192 * 64 + 255) / 256, 256, 0, stream>>>(W0, Bp0, 192);
  k_pack <<<(256 * 64 + 255) / 256, 256, 0, stream>>>(W1, Bp1, 256);

  for (int t = 0; t < T; ++t) {
    const _Float16* h0r = (t & 1) ? h0b : h0a;
    _Float16*       h0w = (t & 1) ? h0a : h0b;
    const _Float16* h1r = (t & 1) ? h1b : h1a;
    _Float16*       h1w = (t & 1) ? h1a : h1b;
    // layer 0: gather [x_t | h0_old] -> gates -> h0_new, c0
    k_fused<192, true><<<512, 512, 0, stream>>>(rowptr, eg, dinv,
        x + (size_t)t * N_NODES * D_INF, h0r, nullptr,
        Bp0, b0, h0w, c0, nullptr, t);
    // layer 1: gather [h0_new | h1_old] -> gates -> h1_new, c1, out
    k_fused<256, false><<<512, 512, 0, stream>>>(rowptr, eg, dinv,
        nullptr, h0w, h1r,
        Bp1, b1, h1w, c1, out, t);
  }
}